// Round 8
// baseline (176.066 us; speedup 1.0000x reference)
//
#include <hip/hip_runtime.h>
#include <hip/hip_bf16.h>

// Problem constants (setup_inputs): x[1024][512] f32, weight[512][16384] f32, L=32
#define B_DIM 1024
#define D_DIM 512
#define N_DIM 16384
#define GRID_QG 1024   // 256 CUs x 4 blocks/CU: all co-resident (LDS 32K, VGPR<=128)

typedef __attribute__((ext_vector_type(4))) int   i32x4;

// ws layout (f32 indices unless noted):
//   0    : u32 bar[2]   (cnt, flag) -- software grid barrier state, init by k_stats
//   16   : xpart[128]   per-block max|x|
//   256  : wpart[512]   per-block max(|w|, bias)
//   1024 : bias[16384]  bias[n] = sum_k w[k][n]^2 / 32   (ends at f32 idx 17408)
//   byte 73728  : i8 xq[B][D]   (512 KiB)
//   byte 598016 : i8 wqT[N][D]  (8 MiB)
#define IDX_XPART 16
#define IDX_WPART 256
#define IDX_BIAS  1024
#define OFF_XQ    73728
#define OFF_WQT   598016

#define WSTAT_BLOCKS 512
#define XMAX_BLOCKS  128

__device__ inline void gload16(const void* g, void* l) {
  __builtin_amdgcn_global_load_lds((const __attribute__((address_space(1))) void*)g,
                                   (__attribute__((address_space(3))) void*)l, 16, 0, 0);
}

__device__ inline unsigned pack4(float a, float b, float c, float d, float inv) {
  int q0 = (int)rintf(a * inv), q1 = (int)rintf(b * inv);
  int q2 = (int)rintf(c * inv), q3 = (int)rintf(d * inv);
  return (q0 & 255) | ((q1 & 255) << 8) | ((q2 & 255) << 16) | ((unsigned)(q3 & 255) << 24);
}

// Every lane computes all scales from the partials (fmax exact -> order-free).
__device__ inline void compute_scales(const float* __restrict__ ws_f, int lane,
                                      float& sx, float& st, float& s, float& q1) {
  float xm = fmaxf(ws_f[IDX_XPART + lane], ws_f[IDX_XPART + 64 + lane]);
  float wm = 0.f;
  #pragma unroll
  for (int j = 0; j < 8; ++j)
    wm = fmaxf(wm, ws_f[IDX_WPART + lane + 64 * j]);
  #pragma unroll
  for (int i = 1; i < 64; i <<= 1) {
    xm = fmaxf(xm, __shfl_xor(xm, i, 64));
    wm = fmaxf(wm, __shfl_xor(wm, i, 64));
  }
  st = fmaxf(wm / 127.0f, 1e-12f);
  sx = fmaxf(fmaxf(xm, 1.0f) / 127.0f, 1e-12f);   // x padded with ones
  s = sx * st;
  q1 = rintf(1.0f / sx);
}

// blocks [0,512): w-stats, 32 cols each (float4 cols, 32 row-parts of 16)
// blocks [512,640): x-max, 4 float4 per thread
// block 0 also re-initializes the grid-barrier words for k_qgemm (each call).
__global__ __launch_bounds__(256) void k_stats(const float* __restrict__ x,
                                               const float* __restrict__ w,
                                               float* __restrict__ ws_f,
                                               unsigned* __restrict__ bar) {
  const int t = threadIdx.x;
  const int b = blockIdx.x;
  if (b == 0 && t == 0) { bar[0] = 0u; bar[1] = 0u; }
  if (b < WSTAT_BLOCKS) {
    __shared__ float4 s4[256], m4[256];
    const int cg = t & 7, part = t >> 3;            // 8 col-groups x 32 row-parts
    const int col = b * 32 + cg * 4;
    const float4* p = (const float4*)(w + (size_t)(part * 16) * N_DIM + col);
    float4 ss = {0.f, 0.f, 0.f, 0.f}, mx = {0.f, 0.f, 0.f, 0.f};
    #pragma unroll
    for (int d = 0; d < 16; ++d) {
      float4 v = p[(size_t)d * (N_DIM / 4)];
      ss.x += v.x * v.x; ss.y += v.y * v.y; ss.z += v.z * v.z; ss.w += v.w * v.w;
      mx.x = fmaxf(mx.x, fabsf(v.x)); mx.y = fmaxf(mx.y, fabsf(v.y));
      mx.z = fmaxf(mx.z, fabsf(v.z)); mx.w = fmaxf(mx.w, fabsf(v.w));
    }
    s4[t] = ss; m4[t] = mx;
    __syncthreads();
    #pragma unroll
    for (int s = 128; s >= 8; s >>= 1) {
      if (t < s) {
        float4 a = s4[t], c = s4[t + s];
        a.x += c.x; a.y += c.y; a.z += c.z; a.w += c.w; s4[t] = a;
        float4 ma = m4[t], mc = m4[t + s];
        ma.x = fmaxf(ma.x, mc.x); ma.y = fmaxf(ma.y, mc.y);
        ma.z = fmaxf(ma.z, mc.z); ma.w = fmaxf(ma.w, mc.w);
        m4[t] = ma;
      }
      __syncthreads();
    }
    if (t < 8) {
      float4 bs = s4[t];
      bs.x *= (1.0f / 32.0f); bs.y *= (1.0f / 32.0f);
      bs.z *= (1.0f / 32.0f); bs.w *= (1.0f / 32.0f);
      const int c0 = b * 32 + t * 4;
      ws_f[IDX_BIAS + c0 + 0] = bs.x; ws_f[IDX_BIAS + c0 + 1] = bs.y;
      ws_f[IDX_BIAS + c0 + 2] = bs.z; ws_f[IDX_BIAS + c0 + 3] = bs.w;
      float4 mm = m4[t];
      // bias >= 0; scale = max over concat(w, bias rows)
      float m = fmaxf(fmaxf(fmaxf(mm.x, bs.x), fmaxf(mm.y, bs.y)),
                      fmaxf(fmaxf(mm.z, bs.z), fmaxf(mm.w, bs.w)));
      #pragma unroll
      for (int i = 1; i < 8; i <<= 1) m = fmaxf(m, __shfl_xor(m, i, 64));
      if (t == 0) ws_f[IDX_WPART + b] = m;
    }
  } else {
    __shared__ float red[4];
    const float4* x4 = (const float4*)x;
    const int base = (b - WSTAT_BLOCKS) * 1024 + t;
    float m = 0.f;
    #pragma unroll
    for (int j = 0; j < 4; ++j) {
      float4 v = x4[base + j * 256];
      m = fmaxf(m, fmaxf(fmaxf(fabsf(v.x), fabsf(v.y)), fmaxf(fabsf(v.z), fabsf(v.w))));
    }
    #pragma unroll
    for (int i = 1; i < 64; i <<= 1) m = fmaxf(m, __shfl_xor(m, i, 64));
    if ((t & 63) == 0) red[t >> 6] = m;
    __syncthreads();
    if (t == 0)
      ws_f[IDX_XPART + (b - WSTAT_BLOCKS)] =
          fmaxf(fmaxf(red[0], red[1]), fmaxf(red[2], red[3]));
  }
}

// ---------------- fused quant -> grid barrier -> i8 GEMM ----------------
// quant: blocks [0,512) also quantize x (1 float4/thread); all 1024 blocks
// transpose-quantize 2 w-tiles (64n x 64k) each.
// GEMM: 128x128 tile, BK=64, 4 waves (2x2), dbuf, chunk-swizzled LDS (R7 body).
#define NT 8   // 512 / 64

// stage one K-64 tile: per wave 32 rows of A and of B (2 issues each, 16 rows/issue)
__device__ inline void stage(const char* __restrict__ xq, const char* __restrict__ wqT,
                             int m0, int n0, int kbase, char* buf, int w, int lane) {
  const int rl = lane >> 2;
  const int kc = ((lane & 3) ^ (rl & 3)) * 16;
  #pragma unroll
  for (int i = 0; i < 2; ++i) {
    const int r0 = w * 32 + i * 16;
    gload16(xq + (size_t)(m0 + r0 + rl) * D_DIM + kbase + kc, buf + r0 * 64);
    gload16(wqT + (size_t)(n0 + r0 + rl) * D_DIM + kbase + kc, buf + 8192 + r0 * 64);
  }
}

__global__ __launch_bounds__(256, 4) void k_qgemm(const float* __restrict__ x,
                                                  const float* __restrict__ w,
                                                  float* __restrict__ ws_f,
                                                  unsigned* __restrict__ xq,
                                                  unsigned* __restrict__ wqT,
                                                  float* __restrict__ out,
                                                  unsigned* __restrict__ bar) {
  __shared__ __align__(16) char smem[32768];
  const int b = blockIdx.x, t = threadIdx.x;
  const int lane = t & 63, wv = t >> 6;

  float sx, st, s, q1;
  compute_scales(ws_f, lane, sx, st, s, q1);

  // ---- phase 1: quantize ----
  if (b < 512) {   // x quant: one float4 -> one packed u32 per thread
    const float inv = 1.0f / sx;
    const int i = b * 256 + t;
    float4 v = ((const float4*)x)[i];
    xq[i] = pack4(v.x, v.y, v.z, v.w, inv);
  }
  {
    float (*tile)[65] = (float (*)[65])smem;   // 16.6 KiB
    const float inv = 1.0f / st;
    const int r_l = t >> 4, c_l = (t & 15) * 4;
    const int kg = t & 15, nr = t >> 4;
    #pragma unroll
    for (int rep = 0; rep < 2; ++rep) {
      const int tid = b * 2 + rep;               // 2048 transpose tiles of 64n x 64k
      const int n0 = (tid & 255) * 64, k0 = (tid >> 8) * 64;
      __syncthreads();                           // protect smem reuse
      #pragma unroll
      for (int pass = 0; pass < 4; ++pass) {
        const int r = pass * 16 + r_l;
        float4 v = *(const float4*)&w[(size_t)(k0 + r) * N_DIM + n0 + c_l];
        tile[r][c_l + 0] = v.x; tile[r][c_l + 1] = v.y;
        tile[r][c_l + 2] = v.z; tile[r][c_l + 3] = v.w;
      }
      __syncthreads();
      #pragma unroll
      for (int it = 0; it < 4; ++it) {
        const int nl = it * 16 + nr;
        wqT[((size_t)(n0 + nl) * D_DIM + k0 + kg * 4) >> 2] =
            pack4(tile[kg * 4 + 0][nl], tile[kg * 4 + 1][nl],
                  tile[kg * 4 + 2][nl], tile[kg * 4 + 3][nl], inv);
      }
    }
  }

  // ---- grid barrier (all 1024 blocks co-resident by construction) ----
  __threadfence();                 // agent-release: drain xq/wqT to coherence point
  __syncthreads();
  if (t == 0) {
    if (atomicAdd(&bar[0], 1u) + 1u == (unsigned)GRID_QG) {
      __hip_atomic_store(&bar[1], 1u, __ATOMIC_RELEASE, __HIP_MEMORY_SCOPE_AGENT);
    } else {
      while (!__hip_atomic_load(&bar[1], __ATOMIC_ACQUIRE, __HIP_MEMORY_SCOPE_AGENT))
        __builtin_amdgcn_s_sleep(4);
    }
  }
  __syncthreads();

  // ---- phase 2: i8 GEMM (R7 body) ----
  const char* xq8 = (const char*)xq;
  const char* wqT8 = (const char*)wqT;
  char* lds = smem;
  const int wm = wv >> 1, wn = wv & 1;
  // XCD-chunked swizzle: each XCD gets 16 consecutive n-panels x all 8 m-panels.
  const int nid = (b & 7) * 128 + (b >> 3);
  const int m0 = (nid & 7) * 128;
  const int n0 = (nid >> 3) * 128;

  stage(xq8, wqT8, m0, n0, 0, &lds[0], wv, lane);

  i32x4 acc[4][4] = {};

  for (int T = 0; T < NT; ++T) {
    char* buf = &lds[(T & 1) * 16384];
    asm volatile("s_waitcnt vmcnt(0)" ::: "memory");   // tile T landed (mine)
    __builtin_amdgcn_s_barrier();                      // all landed; all done reading buf^1
    if (T + 1 < NT)
      stage(xq8, wqT8, m0, n0, (T + 1) * 64, &lds[((T + 1) & 1) * 16384], wv, lane);
    i32x4 af[4], bfr[4];
    #pragma unroll
    for (int f = 0; f < 4; ++f) {
      const int ra = wm * 64 + f * 16 + (lane & 15);
      af[f] = *(const i32x4*)&buf[ra * 64 + (((lane >> 4) ^ (ra & 3))) * 16];
      const int rb = wn * 64 + f * 16 + (lane & 15);
      bfr[f] = *(const i32x4*)&buf[8192 + rb * 64 + (((lane >> 4) ^ (rb & 3))) * 16];
    }
    __builtin_amdgcn_s_setprio(1);
    #pragma unroll
    for (int fm = 0; fm < 4; ++fm)
      #pragma unroll
      for (int fn = 0; fn < 4; ++fn)
        acc[fm][fn] = __builtin_amdgcn_mfma_i32_16x16x64_i8(af[fm], bfr[fn], acc[fm][fn], 0, 0, 0);
    __builtin_amdgcn_s_setprio(0);
    __builtin_amdgcn_sched_barrier(0);
  }

  // epilogue: C/D layout col=lane&15, row=(lane>>4)*4+reg; bias term folded in
  #pragma unroll
  for (int fn = 0; fn < 4; ++fn) {
    const int col = n0 + wn * 64 + fn * 16 + (lane & 15);
    const float ba = 32.0f * q1 * rintf(ws_f[IDX_BIAS + col] / st);
    #pragma unroll
    for (int fm = 0; fm < 4; ++fm) {
      const int rbase = m0 + wm * 64 + fm * 16 + ((lane >> 4) * 4);
      #pragma unroll
      for (int r = 0; r < 4; ++r)
        out[(size_t)(rbase + r) * N_DIM + col] = ((float)acc[fm][fn][r] + ba) * s;
    }
  }
}

extern "C" void kernel_launch(void* const* d_in, const int* in_sizes, int n_in,
                              void* d_out, int out_size, void* d_ws, size_t ws_size,
                              hipStream_t stream) {
  const float* x = (const float*)d_in[0];
  const float* w = (const float*)d_in[1];
  float* out = (float*)d_out;
  char* ws = (char*)d_ws;
  float* ws_f = (float*)ws;
  unsigned* bar = (unsigned*)ws;
  unsigned* xq = (unsigned*)(ws + OFF_XQ);
  unsigned* wqT = (unsigned*)(ws + OFF_WQT);

  hipLaunchKernelGGL(k_stats, dim3(WSTAT_BLOCKS + XMAX_BLOCKS), dim3(256), 0, stream,
                     x, w, ws_f, bar);
  hipLaunchKernelGGL(k_qgemm, dim3(GRID_QG), dim3(256), 0, stream,
                     x, w, ws_f, xq, wqT, out, bar);
}

// Round 9
// 163.347 us; speedup vs baseline: 1.0779x; 1.0779x over previous
//
#include <hip/hip_runtime.h>
#include <hip/hip_bf16.h>

// Problem constants (setup_inputs): x[1024][512] f32, weight[512][16384] f32, L=32
#define B_DIM 1024
#define D_DIM 512
#define N_DIM 16384
#define GRID_QG 1024   // 256 CUs x 4 blocks/CU: all co-resident (LDS 32K, VGPR<=128)

typedef __attribute__((ext_vector_type(4))) int   i32x4;

// ws layout:
//   u32 idx 0..231 : barrier group counters cnt[g] at idx g*32 (128B apart)
//   u32 idx 256    : barrier root counter
//   u32 idx 288    : barrier release flag
//   f32 idx 512    : xpart[128]   per-block max|x|
//   f32 idx 768    : wpart[512]   per-block max(|w|, bias)
//   f32 idx 1536   : bias[16384]  bias[n] = sum_k w[k][n]^2 / 32
//   byte 73728     : i8 xq[B][D]   (512 KiB)
//   byte 598016    : i8 wqT[N][D]  (8 MiB)
#define IDX_XPART 512
#define IDX_WPART 768
#define IDX_BIAS  1536
#define OFF_XQ    73728
#define OFF_WQT   598016

#define WSTAT_BLOCKS 512
#define XMAX_BLOCKS  128

__device__ inline void gload16(const void* g, void* l) {
  __builtin_amdgcn_global_load_lds((const __attribute__((address_space(1))) void*)g,
                                   (__attribute__((address_space(3))) void*)l, 16, 0, 0);
}

__device__ inline unsigned pack4(float a, float b, float c, float d, float inv) {
  int q0 = (int)rintf(a * inv), q1 = (int)rintf(b * inv);
  int q2 = (int)rintf(c * inv), q3 = (int)rintf(d * inv);
  return (q0 & 255) | ((q1 & 255) << 8) | ((q2 & 255) << 16) | ((unsigned)(q3 & 255) << 24);
}

// Every lane computes all scales from the partials (fmax exact -> order-free).
__device__ inline void compute_scales(const float* __restrict__ ws_f, int lane,
                                      float& sx, float& st, float& s, float& q1) {
  float xm = fmaxf(ws_f[IDX_XPART + lane], ws_f[IDX_XPART + 64 + lane]);
  float wm = 0.f;
  #pragma unroll
  for (int j = 0; j < 8; ++j)
    wm = fmaxf(wm, ws_f[IDX_WPART + lane + 64 * j]);
  #pragma unroll
  for (int i = 1; i < 64; i <<= 1) {
    xm = fmaxf(xm, __shfl_xor(xm, i, 64));
    wm = fmaxf(wm, __shfl_xor(wm, i, 64));
  }
  st = fmaxf(wm / 127.0f, 1e-12f);
  sx = fmaxf(fmaxf(xm, 1.0f) / 127.0f, 1e-12f);   // x padded with ones
  s = sx * st;
  q1 = rintf(1.0f / sx);
}

// blocks [0,512): w-stats, 32 cols each (float4 cols, 32 row-parts of 16)
// blocks [512,640): x-max, 4 float4 per thread
// block 0 re-initializes the grid-barrier words for k_qgemm (every call).
__global__ __launch_bounds__(256) void k_stats(const float* __restrict__ x,
                                               const float* __restrict__ w,
                                               float* __restrict__ ws_f,
                                               unsigned* __restrict__ bar) {
  const int t = threadIdx.x;
  const int b = blockIdx.x;
  if (b == 0 && t < 10) bar[t < 8 ? t * 32 : (t == 8 ? 256 : 288)] = 0u;
  if (b < WSTAT_BLOCKS) {
    __shared__ float4 s4[256], m4[256];
    const int cg = t & 7, part = t >> 3;            // 8 col-groups x 32 row-parts
    const int col = b * 32 + cg * 4;
    const float4* p = (const float4*)(w + (size_t)(part * 16) * N_DIM + col);
    float4 ss = {0.f, 0.f, 0.f, 0.f}, mx = {0.f, 0.f, 0.f, 0.f};
    #pragma unroll
    for (int d = 0; d < 16; ++d) {
      float4 v = p[(size_t)d * (N_DIM / 4)];
      ss.x += v.x * v.x; ss.y += v.y * v.y; ss.z += v.z * v.z; ss.w += v.w * v.w;
      mx.x = fmaxf(mx.x, fabsf(v.x)); mx.y = fmaxf(mx.y, fabsf(v.y));
      mx.z = fmaxf(mx.z, fabsf(v.z)); mx.w = fmaxf(mx.w, fabsf(v.w));
    }
    s4[t] = ss; m4[t] = mx;
    __syncthreads();
    #pragma unroll
    for (int s = 128; s >= 8; s >>= 1) {
      if (t < s) {
        float4 a = s4[t], c = s4[t + s];
        a.x += c.x; a.y += c.y; a.z += c.z; a.w += c.w; s4[t] = a;
        float4 ma = m4[t], mc = m4[t + s];
        ma.x = fmaxf(ma.x, mc.x); ma.y = fmaxf(ma.y, mc.y);
        ma.z = fmaxf(ma.z, mc.z); ma.w = fmaxf(ma.w, mc.w);
        m4[t] = ma;
      }
      __syncthreads();
    }
    if (t < 8) {
      float4 bs = s4[t];
      bs.x *= (1.0f / 32.0f); bs.y *= (1.0f / 32.0f);
      bs.z *= (1.0f / 32.0f); bs.w *= (1.0f / 32.0f);
      const int c0 = b * 32 + t * 4;
      ws_f[IDX_BIAS + c0 + 0] = bs.x; ws_f[IDX_BIAS + c0 + 1] = bs.y;
      ws_f[IDX_BIAS + c0 + 2] = bs.z; ws_f[IDX_BIAS + c0 + 3] = bs.w;
      float4 mm = m4[t];
      // bias >= 0; scale = max over concat(w, bias rows)
      float m = fmaxf(fmaxf(fmaxf(mm.x, bs.x), fmaxf(mm.y, bs.y)),
                      fmaxf(fmaxf(mm.z, bs.z), fmaxf(mm.w, bs.w)));
      #pragma unroll
      for (int i = 1; i < 8; i <<= 1) m = fmaxf(m, __shfl_xor(m, i, 64));
      if (t == 0) ws_f[IDX_WPART + b] = m;
    }
  } else {
    __shared__ float red[4];
    const float4* x4 = (const float4*)x;
    const int base = (b - WSTAT_BLOCKS) * 1024 + t;
    float m = 0.f;
    #pragma unroll
    for (int j = 0; j < 4; ++j) {
      float4 v = x4[base + j * 256];
      m = fmaxf(m, fmaxf(fmaxf(fabsf(v.x), fabsf(v.y)), fmaxf(fabsf(v.z), fabsf(v.w))));
    }
    #pragma unroll
    for (int i = 1; i < 64; i <<= 1) m = fmaxf(m, __shfl_xor(m, i, 64));
    if ((t & 63) == 0) red[t >> 6] = m;
    __syncthreads();
    if (t == 0)
      ws_f[IDX_XPART + (b - WSTAT_BLOCKS)] =
          fmaxf(fmaxf(red[0], red[1]), fmaxf(red[2], red[3]));
  }
}

// ---------------- fused quant -> grid barrier -> i8 GEMM ----------------
// quant: every block quantizes 128 x-words + transpose-quantizes 2 w-tiles.
// GEMM: 128x128 tile, BK=64, 4 waves (2x2), dbuf.
// LDS chunk swizzle f(r) = (r>>1)&3: LDS[r] position p holds chunk p ^ f(r)
// (chunks of 16 i8 = 16B). Read bank-quads 2-way only (free per m136).
#define NT 8   // 512 / 64

// stage one K-64 tile: per wave 32 rows of A and of B (2 issues each, 16 rows/issue)
__device__ inline void stage(const char* __restrict__ xq, const char* __restrict__ wqT,
                             int m0, int n0, int kbase, char* buf, int w, int lane) {
  const int rl = lane >> 2;
  const int kc = ((lane & 3) ^ ((lane >> 3) & 3)) * 16;   // chunk = pos ^ f(row)
  #pragma unroll
  for (int i = 0; i < 2; ++i) {
    const int r0 = w * 32 + i * 16;
    gload16(xq + (size_t)(m0 + r0 + rl) * D_DIM + kbase + kc, buf + r0 * 64);
    gload16(wqT + (size_t)(n0 + r0 + rl) * D_DIM + kbase + kc, buf + 8192 + r0 * 64);
  }
}

__global__ __launch_bounds__(256, 4) void k_qgemm(const float* __restrict__ x,
                                                  const float* __restrict__ w,
                                                  float* __restrict__ ws_f,
                                                  unsigned* __restrict__ xq,
                                                  unsigned* __restrict__ wqT,
                                                  float* __restrict__ out,
                                                  unsigned* __restrict__ bar) {
  __shared__ __align__(16) char smem[32768];
  const int b = blockIdx.x, t = threadIdx.x;
  const int lane = t & 63, wv = t >> 6;

  float sx, st, s, q1;
  compute_scales(ws_f, lane, sx, st, s, q1);

  // ---- phase 1: quantize ----
  if (t < 128) {   // x quant: 128 packed words per block (1024*128 = all of x)
    const float inv = 1.0f / sx;
    const int i = b * 128 + t;
    float4 v = ((const float4*)x)[i];
    xq[i] = pack4(v.x, v.y, v.z, v.w, inv);
  }
  {
    float (*tile)[65] = (float (*)[65])smem;   // 16.6 KiB
    const float inv = 1.0f / st;
    const int r_l = t >> 4, c_l = (t & 15) * 4;
    const int kg = t & 15, nr = t >> 4;
    #pragma unroll
    for (int rep = 0; rep < 2; ++rep) {
      const int tid = b * 2 + rep;               // 2048 transpose tiles of 64n x 64k
      const int n0 = (tid & 255) * 64, k0 = (tid >> 8) * 64;
      __syncthreads();                           // protect smem reuse
      #pragma unroll
      for (int pass = 0; pass < 4; ++pass) {
        const int r = pass * 16 + r_l;
        float4 v = *(const float4*)&w[(size_t)(k0 + r) * N_DIM + n0 + c_l];
        tile[r][c_l + 0] = v.x; tile[r][c_l + 1] = v.y;
        tile[r][c_l + 2] = v.z; tile[r][c_l + 3] = v.w;
      }
      __syncthreads();
      #pragma unroll
      for (int it = 0; it < 4; ++it) {
        const int nl = it * 16 + nr;
        wqT[((size_t)(n0 + nl) * D_DIM + k0 + kg * 4) >> 2] =
            pack4(tile[kg * 4 + 0][nl], tile[kg * 4 + 1][nl],
                  tile[kg * 4 + 2][nl], tile[kg * 4 + 3][nl], inv);
      }
    }
  }

  // ---- grid barrier (all 1024 blocks co-resident by construction) ----
  // Relaxed spin (no per-poll cache maintenance) + one full fence after release.
  __threadfence();                 // release: drain xq/wqT to the coherence point
  __syncthreads();
  if (t == 0) {
    const int g = b >> 7;          // 8 arrival groups x 128 blocks, lines 128B apart
    if (atomicAdd(bar + g * 32, 1u) == 127u) {
      if (atomicAdd(bar + 256, 1u) == 7u)
        __hip_atomic_store(bar + 288, 1u, __ATOMIC_RELAXED, __HIP_MEMORY_SCOPE_AGENT);
    }
    while (!__hip_atomic_load(bar + 288, __ATOMIC_RELAXED, __HIP_MEMORY_SCOPE_AGENT))
      __builtin_amdgcn_s_sleep(64);
    __threadfence();               // acquire: invalidate stale L1/L2 lines once
  }
  __syncthreads();

  // ---- phase 2: i8 GEMM ----
  const char* xq8 = (const char*)xq;
  const char* wqT8 = (const char*)wqT;
  char* lds = smem;
  const int wm = wv >> 1, wn = wv & 1;
  // XCD-chunked swizzle: each XCD gets 16 consecutive n-panels x all 8 m-panels.
  const int nid = (b & 7) * 128 + (b >> 3);
  const int m0 = (nid & 7) * 128;
  const int n0 = (nid >> 3) * 128;

  stage(xq8, wqT8, m0, n0, 0, &lds[0], wv, lane);

  i32x4 acc[4][4] = {};

  for (int T = 0; T < NT; ++T) {
    char* buf = &lds[(T & 1) * 16384];
    asm volatile("s_waitcnt vmcnt(0)" ::: "memory");   // tile T landed (mine)
    __builtin_amdgcn_s_barrier();                      // all landed; all done reading buf^1
    if (T + 1 < NT)
      stage(xq8, wqT8, m0, n0, (T + 1) * 64, &lds[((T + 1) & 1) * 16384], wv, lane);
    i32x4 af[4], bfr[4];
    #pragma unroll
    for (int f = 0; f < 4; ++f) {
      const int ra = wm * 64 + f * 16 + (lane & 15);
      af[f] = *(const i32x4*)&buf[ra * 64 + (((lane >> 4) ^ ((ra >> 1) & 3))) * 16];
      const int rb = wn * 64 + f * 16 + (lane & 15);
      bfr[f] = *(const i32x4*)&buf[8192 + rb * 64 + (((lane >> 4) ^ ((rb >> 1) & 3))) * 16];
    }
    __builtin_amdgcn_s_setprio(1);
    #pragma unroll
    for (int fm = 0; fm < 4; ++fm)
      #pragma unroll
      for (int fn = 0; fn < 4; ++fn)
        acc[fm][fn] = __builtin_amdgcn_mfma_i32_16x16x64_i8(af[fm], bfr[fn], acc[fm][fn], 0, 0, 0);
    __builtin_amdgcn_s_setprio(0);
    __builtin_amdgcn_sched_barrier(0);
  }

  // epilogue: C/D layout col=lane&15, row=(lane>>4)*4+reg; bias term folded in
  #pragma unroll
  for (int fn = 0; fn < 4; ++fn) {
    const int col = n0 + wn * 64 + fn * 16 + (lane & 15);
    const float ba = 32.0f * q1 * rintf(ws_f[IDX_BIAS + col] / st);
    #pragma unroll
    for (int fm = 0; fm < 4; ++fm) {
      const int rbase = m0 + wm * 64 + fm * 16 + ((lane >> 4) * 4);
      #pragma unroll
      for (int r = 0; r < 4; ++r)
        out[(size_t)(rbase + r) * N_DIM + col] = ((float)acc[fm][fn][r] + ba) * s;
    }
  }
}

extern "C" void kernel_launch(void* const* d_in, const int* in_sizes, int n_in,
                              void* d_out, int out_size, void* d_ws, size_t ws_size,
                              hipStream_t stream) {
  const float* x = (const float*)d_in[0];
  const float* w = (const float*)d_in[1];
  float* out = (float*)d_out;
  char* ws = (char*)d_ws;
  float* ws_f = (float*)ws;
  unsigned* bar = (unsigned*)ws;
  unsigned* xq = (unsigned*)(ws + OFF_XQ);
  unsigned* wqT = (unsigned*)(ws + OFF_WQT);

  hipLaunchKernelGGL(k_stats, dim3(WSTAT_BLOCKS + XMAX_BLOCKS), dim3(256), 0, stream,
                     x, w, ws_f, bar);
  hipLaunchKernelGGL(k_qgemm, dim3(GRID_QG), dim3(256), 0, stream,
                     x, w, ws_f, xq, wqT, out, bar);
}

// Round 10
// 46.641 us; speedup vs baseline: 3.7749x; 3.5022x over previous
//
#include <hip/hip_runtime.h>
#include <hip/hip_bf16.h>

// Problem constants (setup_inputs): x[1024][512] f32, weight[512][16384] f32, L=32
#define B_DIM 1024
#define D_DIM 512
#define N_DIM 16384

typedef __attribute__((ext_vector_type(4))) int   i32x4;

// ws layout:
//   f32 idx 512    : xpart[128]   per-block max|x|
//   f32 idx 768    : wpart[512]   per-block max(|w|, bias)
//   f32 idx 1536   : bias[16384]  bias[n] = sum_k w[k][n]^2 / 32
//   byte 73728     : i8 xq[B][D]   (512 KiB)
//   byte 598016    : i8 wqT[N][D]  (8 MiB)
#define IDX_XPART 512
#define IDX_WPART 768
#define IDX_BIAS  1536
#define OFF_XQ    73728
#define OFF_WQT   598016

#define WSTAT_BLOCKS 512
#define XMAX_BLOCKS  128
#define QX_BLOCKS    512   // B*D/4/256

__device__ inline void gload16(const void* g, void* l) {
  __builtin_amdgcn_global_load_lds((const __attribute__((address_space(1))) void*)g,
                                   (__attribute__((address_space(3))) void*)l, 16, 0, 0);
}

__device__ inline unsigned pack4(float a, float b, float c, float d, float inv) {
  int q0 = (int)rintf(a * inv), q1 = (int)rintf(b * inv);
  int q2 = (int)rintf(c * inv), q3 = (int)rintf(d * inv);
  return (q0 & 255) | ((q1 & 255) << 8) | ((q2 & 255) << 16) | ((unsigned)(q3 & 255) << 24);
}

// Every lane computes all scales from the partials (fmax exact -> order-free).
__device__ inline void compute_scales(const float* __restrict__ ws_f, int lane,
                                      float& sx, float& st, float& s, float& q1) {
  float xm = fmaxf(ws_f[IDX_XPART + lane], ws_f[IDX_XPART + 64 + lane]);
  float wm = 0.f;
  #pragma unroll
  for (int j = 0; j < 8; ++j)
    wm = fmaxf(wm, ws_f[IDX_WPART + lane + 64 * j]);
  #pragma unroll
  for (int i = 1; i < 64; i <<= 1) {
    xm = fmaxf(xm, __shfl_xor(xm, i, 64));
    wm = fmaxf(wm, __shfl_xor(wm, i, 64));
  }
  st = fmaxf(wm / 127.0f, 1e-12f);
  sx = fmaxf(fmaxf(xm, 1.0f) / 127.0f, 1e-12f);   // x padded with ones
  s = sx * st;
  q1 = rintf(1.0f / sx);
}

// blocks [0,512): w-stats, 32 cols each (float4 cols, 32 row-parts of 16)
// blocks [512,640): x-max, 4 float4 per thread
__global__ __launch_bounds__(256) void k_stats(const float* __restrict__ x,
                                               const float* __restrict__ w,
                                               float* __restrict__ ws_f) {
  const int t = threadIdx.x;
  const int b = blockIdx.x;
  if (b < WSTAT_BLOCKS) {
    __shared__ float4 s4[256], m4[256];
    const int cg = t & 7, part = t >> 3;            // 8 col-groups x 32 row-parts
    const int col = b * 32 + cg * 4;
    const float4* p = (const float4*)(w + (size_t)(part * 16) * N_DIM + col);
    float4 ss = {0.f, 0.f, 0.f, 0.f}, mx = {0.f, 0.f, 0.f, 0.f};
    #pragma unroll
    for (int d = 0; d < 16; ++d) {
      float4 v = p[(size_t)d * (N_DIM / 4)];
      ss.x += v.x * v.x; ss.y += v.y * v.y; ss.z += v.z * v.z; ss.w += v.w * v.w;
      mx.x = fmaxf(mx.x, fabsf(v.x)); mx.y = fmaxf(mx.y, fabsf(v.y));
      mx.z = fmaxf(mx.z, fabsf(v.z)); mx.w = fmaxf(mx.w, fabsf(v.w));
    }
    s4[t] = ss; m4[t] = mx;
    __syncthreads();
    #pragma unroll
    for (int s = 128; s >= 8; s >>= 1) {
      if (t < s) {
        float4 a = s4[t], c = s4[t + s];
        a.x += c.x; a.y += c.y; a.z += c.z; a.w += c.w; s4[t] = a;
        float4 ma = m4[t], mc = m4[t + s];
        ma.x = fmaxf(ma.x, mc.x); ma.y = fmaxf(ma.y, mc.y);
        ma.z = fmaxf(ma.z, mc.z); ma.w = fmaxf(ma.w, mc.w);
        m4[t] = ma;
      }
      __syncthreads();
    }
    if (t < 8) {
      float4 bs = s4[t];
      bs.x *= (1.0f / 32.0f); bs.y *= (1.0f / 32.0f);
      bs.z *= (1.0f / 32.0f); bs.w *= (1.0f / 32.0f);
      const int c0 = b * 32 + t * 4;
      ws_f[IDX_BIAS + c0 + 0] = bs.x; ws_f[IDX_BIAS + c0 + 1] = bs.y;
      ws_f[IDX_BIAS + c0 + 2] = bs.z; ws_f[IDX_BIAS + c0 + 3] = bs.w;
      float4 mm = m4[t];
      // bias >= 0; scale = max over concat(w, bias rows)
      float m = fmaxf(fmaxf(fmaxf(mm.x, bs.x), fmaxf(mm.y, bs.y)),
                      fmaxf(fmaxf(mm.z, bs.z), fmaxf(mm.w, bs.w)));
      #pragma unroll
      for (int i = 1; i < 8; i <<= 1) m = fmaxf(m, __shfl_xor(m, i, 64));
      if (t == 0) ws_f[IDX_WPART + b] = m;
    }
  } else {
    __shared__ float red[4];
    const float4* x4 = (const float4*)x;
    const int base = (b - WSTAT_BLOCKS) * 1024 + t;
    float m = 0.f;
    #pragma unroll
    for (int j = 0; j < 4; ++j) {
      float4 v = x4[base + j * 256];
      m = fmaxf(m, fmaxf(fmaxf(fabsf(v.x), fabsf(v.y)), fmaxf(fabsf(v.z), fabsf(v.w))));
    }
    #pragma unroll
    for (int i = 1; i < 64; i <<= 1) m = fmaxf(m, __shfl_xor(m, i, 64));
    if ((t & 63) == 0) red[t >> 6] = m;
    __syncthreads();
    if (t == 0)
      ws_f[IDX_XPART + (b - WSTAT_BLOCKS)] =
          fmaxf(fmaxf(red[0], red[1]), fmaxf(red[2], red[3]));
  }
}

// blocks [0,512): quantize x -> xq i8
// blocks [512,2560): quantize + transpose w -> wqT[n][k] i8
__global__ __launch_bounds__(256) void k_quant(const float* __restrict__ x,
                                               const float* __restrict__ w,
                                               const float* __restrict__ ws_f,
                                               unsigned* __restrict__ xq,
                                               unsigned* __restrict__ wqT) {
  const int t = threadIdx.x;
  float sx, st, s_u, q1_u;
  compute_scales(ws_f, t & 63, sx, st, s_u, q1_u);
  if (blockIdx.x < QX_BLOCKS) {
    const int i = blockIdx.x * 256 + t;   // one float4 -> one packed u32 per thread
    const float inv = 1.0f / sx;
    float4 v = ((const float4*)x)[i];
    xq[i] = pack4(v.x, v.y, v.z, v.w, inv);
  } else {
    __shared__ float tile[64][65];
    const int bid = blockIdx.x - QX_BLOCKS;
    const int n0 = (bid & 255) * 64, k0 = (bid >> 8) * 64;
    const float inv = 1.0f / st;
    {
      // float4 loads: 4 passes, row = pass*16 + (t>>4), cols (t&15)*4
      const int r_l = t >> 4, c_l = (t & 15) * 4;
      #pragma unroll
      for (int pass = 0; pass < 4; ++pass) {
        const int r = pass * 16 + r_l;
        float4 v = *(const float4*)&w[(size_t)(k0 + r) * N_DIM + n0 + c_l];
        tile[r][c_l + 0] = v.x; tile[r][c_l + 1] = v.y;
        tile[r][c_l + 2] = v.z; tile[r][c_l + 3] = v.w;
      }
    }
    __syncthreads();
    // thread -> (k-group kg of 4, n-row nl); LDS reads conflict-free (65 pad)
    const int kg = t & 15, nr = t >> 4;
    #pragma unroll
    for (int it = 0; it < 4; ++it) {
      const int nl = it * 16 + nr;
      wqT[((size_t)(n0 + nl) * D_DIM + k0 + kg * 4) >> 2] =
          pack4(tile[kg * 4 + 0][nl], tile[kg * 4 + 1][nl],
                tile[kg * 4 + 2][nl], tile[kg * 4 + 3][nl], inv);
    }
  }
}

// ---------------- GEMM (i8): 128x128 tile, BK=64, 4 waves (2x2), dbuf ----------------
// out[b][n] = ((i32) sum_k qx[b][k]*qw[n][k] + 32*q1*rint(bias[n]/st)) * s
// LDS: 2 x 16 KiB buffers, but 64 KiB ALLOCATED on purpose: throttles residency to
// 2 blocks/CU so the 1024 blocks run as TWO generations -- gen-1's 64 MB epilogue
// write burst overlaps gen-2's staging+MFMA (all-co-resident R7 had a serialized
// write tail with nothing to overlap it).
// Chunk swizzle f(r)=(r>>1)&3: LDS[r] position p holds chunk p ^ f(r) (16B chunks);
// read bank-quads are uniformly spread (R9: conflicts 1.57M -> 0.52M).
#define NT 8   // 512 / 64

// stage one K-64 tile: per wave 32 rows of A and of B (2 issues each, 16 rows/issue)
__device__ inline void stage(const char* __restrict__ xq, const char* __restrict__ wqT,
                             int m0, int n0, int kbase, char* buf, int w, int lane) {
  const int rl = lane >> 2;
  const int kc = ((lane & 3) ^ ((lane >> 3) & 3)) * 16;   // chunk = pos ^ f(row)
  #pragma unroll
  for (int i = 0; i < 2; ++i) {
    const int r0 = w * 32 + i * 16;
    gload16(xq + (size_t)(m0 + r0 + rl) * D_DIM + kbase + kc, buf + r0 * 64);
    gload16(wqT + (size_t)(n0 + r0 + rl) * D_DIM + kbase + kc, buf + 8192 + r0 * 64);
  }
}

__global__ __launch_bounds__(256, 2) void k_gemm(const char* __restrict__ xq,
                                                 const char* __restrict__ wqT,
                                                 const float* __restrict__ ws_f,
                                                 float* __restrict__ out) {
  __shared__ __align__(16) char lds[65536];   // only [0,32768) used; rest = throttle
  const int t = threadIdx.x;
  const int lane = t & 63, w = t >> 6;
  const int wm = w >> 1, wn = w & 1;
  // XCD-chunked swizzle: each XCD gets 16 consecutive n-panels x all 8 m-panels.
  const int nid = (blockIdx.x & 7) * 128 + (blockIdx.x >> 3);
  const int m0 = (nid & 7) * 128;
  const int n0 = (nid >> 3) * 128;

  // prologue: stage tile 0 into buf 0; scales reduce under the loads
  stage(xq, wqT, m0, n0, 0, &lds[0], w, lane);
  float sx_u, st, s, q1;
  compute_scales(ws_f, lane, sx_u, st, s, q1);

  i32x4 acc[4][4] = {};

  for (int T = 0; T < NT; ++T) {
    char* buf = &lds[(T & 1) * 16384];
    asm volatile("s_waitcnt vmcnt(0)" ::: "memory");   // tile T landed (mine)
    __builtin_amdgcn_s_barrier();                      // all landed; all done reading buf^1
    if (T + 1 < NT)
      stage(xq, wqT, m0, n0, (T + 1) * 64, &lds[((T + 1) & 1) * 16384], w, lane);
    i32x4 af[4], bfr[4];
    #pragma unroll
    for (int f = 0; f < 4; ++f) {
      const int ra = wm * 64 + f * 16 + (lane & 15);
      af[f] = *(const i32x4*)&buf[ra * 64 + (((lane >> 4) ^ ((ra >> 1) & 3))) * 16];
      const int rb = wn * 64 + f * 16 + (lane & 15);
      bfr[f] = *(const i32x4*)&buf[8192 + rb * 64 + (((lane >> 4) ^ ((rb >> 1) & 3))) * 16];
    }
    __builtin_amdgcn_s_setprio(1);
    #pragma unroll
    for (int fm = 0; fm < 4; ++fm)
      #pragma unroll
      for (int fn = 0; fn < 4; ++fn)
        acc[fm][fn] = __builtin_amdgcn_mfma_i32_16x16x64_i8(af[fm], bfr[fn], acc[fm][fn], 0, 0, 0);
    __builtin_amdgcn_s_setprio(0);
    __builtin_amdgcn_sched_barrier(0);
  }

  // epilogue: C/D layout col=lane&15, row=(lane>>4)*4+reg; bias term folded in.
  // Nontemporal stores: out is write-once, keep it out of L2 (xq/wqT panels stay).
  #pragma unroll
  for (int fn = 0; fn < 4; ++fn) {
    const int col = n0 + wn * 64 + fn * 16 + (lane & 15);
    const float ba = 32.0f * q1 * rintf(ws_f[IDX_BIAS + col] / st);
    #pragma unroll
    for (int fm = 0; fm < 4; ++fm) {
      const int rbase = m0 + wm * 64 + fm * 16 + ((lane >> 4) * 4);
      #pragma unroll
      for (int r = 0; r < 4; ++r)
        __builtin_nontemporal_store(((float)acc[fm][fn][r] + ba) * s,
                                    &out[(size_t)(rbase + r) * N_DIM + col]);
    }
  }
}

extern "C" void kernel_launch(void* const* d_in, const int* in_sizes, int n_in,
                              void* d_out, int out_size, void* d_ws, size_t ws_size,
                              hipStream_t stream) {
  const float* x = (const float*)d_in[0];
  const float* w = (const float*)d_in[1];
  float* out = (float*)d_out;
  char* ws = (char*)d_ws;
  float* ws_f = (float*)ws;
  unsigned* xq = (unsigned*)(ws + OFF_XQ);
  unsigned* wqT = (unsigned*)(ws + OFF_WQT);

  hipLaunchKernelGGL(k_stats, dim3(WSTAT_BLOCKS + XMAX_BLOCKS), dim3(256), 0, stream,
                     x, w, ws_f);
  hipLaunchKernelGGL(k_quant, dim3(QX_BLOCKS + 2048), dim3(256), 0, stream,
                     x, w, ws_f, xq, wqT);
  hipLaunchKernelGGL(k_gemm, dim3((B_DIM / 128) * (N_DIM / 128)), dim3(256), 0, stream,
                     (const char*)xq, (const char*)wqT, ws_f, out);
}

// Round 11
// 41.589 us; speedup vs baseline: 4.2334x; 1.1215x over previous
//
#include <hip/hip_runtime.h>
#include <hip/hip_bf16.h>

// Problem constants (setup_inputs): x[1024][512] f32, weight[512][16384] f32, L=32
#define B_DIM 1024
#define D_DIM 512
#define N_DIM 16384

typedef __attribute__((ext_vector_type(4))) int   i32x4;

// ws layout:
//   f32 idx 512    : xpart[128]   per-block max|x|
//   f32 idx 768    : wpart[512]   per-block max(|w|, bias)
//   f32 idx 1536   : bias[16384]  bias[n] = sum_k w[k][n]^2 / 32
//   byte 73728     : i8 xq[B][D]   (512 KiB)
//   byte 598016    : i8 wqT[N][D]  (8 MiB)
#define IDX_XPART 512
#define IDX_WPART 768
#define IDX_BIAS  1536
#define OFF_XQ    73728
#define OFF_WQT   598016

#define WSTAT_BLOCKS 512
#define XMAX_BLOCKS  128
#define QX_BLOCKS    512   // B*D/4/256

__device__ inline void gload16(const void* g, void* l) {
  __builtin_amdgcn_global_load_lds((const __attribute__((address_space(1))) void*)g,
                                   (__attribute__((address_space(3))) void*)l, 16, 0, 0);
}

__device__ inline unsigned pack4(float a, float b, float c, float d, float inv) {
  int q0 = (int)rintf(a * inv), q1 = (int)rintf(b * inv);
  int q2 = (int)rintf(c * inv), q3 = (int)rintf(d * inv);
  return (q0 & 255) | ((q1 & 255) << 8) | ((q2 & 255) << 16) | ((unsigned)(q3 & 255) << 24);
}

// Every lane computes all scales from the partials (fmax exact -> order-free).
__device__ inline void compute_scales(const float* __restrict__ ws_f, int lane,
                                      float& sx, float& st, float& s, float& q1) {
  float xm = fmaxf(ws_f[IDX_XPART + lane], ws_f[IDX_XPART + 64 + lane]);
  float wm = 0.f;
  #pragma unroll
  for (int j = 0; j < 8; ++j)
    wm = fmaxf(wm, ws_f[IDX_WPART + lane + 64 * j]);
  #pragma unroll
  for (int i = 1; i < 64; i <<= 1) {
    xm = fmaxf(xm, __shfl_xor(xm, i, 64));
    wm = fmaxf(wm, __shfl_xor(wm, i, 64));
  }
  st = fmaxf(wm / 127.0f, 1e-12f);
  sx = fmaxf(fmaxf(xm, 1.0f) / 127.0f, 1e-12f);   // x padded with ones
  s = sx * st;
  q1 = rintf(1.0f / sx);
}

// blocks [0,512): w-stats, 32 cols each (float4 cols, 32 row-parts of 16)
// blocks [512,640): x-max, 4 float4 per thread
__global__ __launch_bounds__(256) void k_stats(const float* __restrict__ x,
                                               const float* __restrict__ w,
                                               float* __restrict__ ws_f) {
  const int t = threadIdx.x;
  const int b = blockIdx.x;
  if (b < WSTAT_BLOCKS) {
    __shared__ float4 s4[256], m4[256];
    const int cg = t & 7, part = t >> 3;            // 8 col-groups x 32 row-parts
    const int col = b * 32 + cg * 4;
    const float4* p = (const float4*)(w + (size_t)(part * 16) * N_DIM + col);
    float4 ss = {0.f, 0.f, 0.f, 0.f}, mx = {0.f, 0.f, 0.f, 0.f};
    #pragma unroll
    for (int d = 0; d < 16; ++d) {
      float4 v = p[(size_t)d * (N_DIM / 4)];
      ss.x += v.x * v.x; ss.y += v.y * v.y; ss.z += v.z * v.z; ss.w += v.w * v.w;
      mx.x = fmaxf(mx.x, fabsf(v.x)); mx.y = fmaxf(mx.y, fabsf(v.y));
      mx.z = fmaxf(mx.z, fabsf(v.z)); mx.w = fmaxf(mx.w, fabsf(v.w));
    }
    s4[t] = ss; m4[t] = mx;
    __syncthreads();
    #pragma unroll
    for (int s = 128; s >= 8; s >>= 1) {
      if (t < s) {
        float4 a = s4[t], c = s4[t + s];
        a.x += c.x; a.y += c.y; a.z += c.z; a.w += c.w; s4[t] = a;
        float4 ma = m4[t], mc = m4[t + s];
        ma.x = fmaxf(ma.x, mc.x); ma.y = fmaxf(ma.y, mc.y);
        ma.z = fmaxf(ma.z, mc.z); ma.w = fmaxf(ma.w, mc.w);
        m4[t] = ma;
      }
      __syncthreads();
    }
    if (t < 8) {
      float4 bs = s4[t];
      bs.x *= (1.0f / 32.0f); bs.y *= (1.0f / 32.0f);
      bs.z *= (1.0f / 32.0f); bs.w *= (1.0f / 32.0f);
      const int c0 = b * 32 + t * 4;
      ws_f[IDX_BIAS + c0 + 0] = bs.x; ws_f[IDX_BIAS + c0 + 1] = bs.y;
      ws_f[IDX_BIAS + c0 + 2] = bs.z; ws_f[IDX_BIAS + c0 + 3] = bs.w;
      float4 mm = m4[t];
      // bias >= 0; scale = max over concat(w, bias rows)
      float m = fmaxf(fmaxf(fmaxf(mm.x, bs.x), fmaxf(mm.y, bs.y)),
                      fmaxf(fmaxf(mm.z, bs.z), fmaxf(mm.w, bs.w)));
      #pragma unroll
      for (int i = 1; i < 8; i <<= 1) m = fmaxf(m, __shfl_xor(m, i, 64));
      if (t == 0) ws_f[IDX_WPART + b] = m;
    }
  } else {
    __shared__ float red[4];
    const float4* x4 = (const float4*)x;
    const int base = (b - WSTAT_BLOCKS) * 1024 + t;
    float m = 0.f;
    #pragma unroll
    for (int j = 0; j < 4; ++j) {
      float4 v = x4[base + j * 256];
      m = fmaxf(m, fmaxf(fmaxf(fabsf(v.x), fabsf(v.y)), fmaxf(fabsf(v.z), fabsf(v.w))));
    }
    #pragma unroll
    for (int i = 1; i < 64; i <<= 1) m = fmaxf(m, __shfl_xor(m, i, 64));
    if ((t & 63) == 0) red[t >> 6] = m;
    __syncthreads();
    if (t == 0)
      ws_f[IDX_XPART + (b - WSTAT_BLOCKS)] =
          fmaxf(fmaxf(red[0], red[1]), fmaxf(red[2], red[3]));
  }
}

// blocks [0,512): quantize x -> xq i8
// blocks [512,2560): quantize + transpose w -> wqT[n][k] i8
__global__ __launch_bounds__(256) void k_quant(const float* __restrict__ x,
                                               const float* __restrict__ w,
                                               const float* __restrict__ ws_f,
                                               unsigned* __restrict__ xq,
                                               unsigned* __restrict__ wqT) {
  const int t = threadIdx.x;
  float sx, st, s_u, q1_u;
  compute_scales(ws_f, t & 63, sx, st, s_u, q1_u);
  if (blockIdx.x < QX_BLOCKS) {
    const int i = blockIdx.x * 256 + t;   // one float4 -> one packed u32 per thread
    const float inv = 1.0f / sx;
    float4 v = ((const float4*)x)[i];
    xq[i] = pack4(v.x, v.y, v.z, v.w, inv);
  } else {
    __shared__ float tile[64][65];
    const int bid = blockIdx.x - QX_BLOCKS;
    const int n0 = (bid & 255) * 64, k0 = (bid >> 8) * 64;
    const float inv = 1.0f / st;
    {
      // float4 loads: 4 passes, row = pass*16 + (t>>4), cols (t&15)*4
      const int r_l = t >> 4, c_l = (t & 15) * 4;
      #pragma unroll
      for (int pass = 0; pass < 4; ++pass) {
        const int r = pass * 16 + r_l;
        float4 v = *(const float4*)&w[(size_t)(k0 + r) * N_DIM + n0 + c_l];
        tile[r][c_l + 0] = v.x; tile[r][c_l + 1] = v.y;
        tile[r][c_l + 2] = v.z; tile[r][c_l + 3] = v.w;
      }
    }
    __syncthreads();
    // thread -> (k-group kg of 4, n-row nl); LDS reads conflict-free (65 pad)
    const int kg = t & 15, nr = t >> 4;
    #pragma unroll
    for (int it = 0; it < 4; ++it) {
      const int nl = it * 16 + nr;
      wqT[((size_t)(n0 + nl) * D_DIM + k0 + kg * 4) >> 2] =
          pack4(tile[kg * 4 + 0][nl], tile[kg * 4 + 1][nl],
                tile[kg * 4 + 2][nl], tile[kg * 4 + 3][nl], inv);
    }
  }
}

// ---------------- GEMM (i8): 128x128 tile, BK=64, 4 waves (2x2), dbuf ----------------
// out[b][n] = ((i32) sum_k qx[b][k]*qw[n][k] + 32*q1*rint(bias[n]/st)) * s
// R7 configuration (proven 41.4 us): 32 KiB LDS -> 4 blocks/CU, single generation,
// plain stores. One kept improvement: chunk swizzle f(r)=(r>>1)&3 (R8->R9 A/B:
// SQ_LDS_BANK_CONFLICT 1.57M -> 0.52M on the identical GEMM phase).
#define NT 8   // 512 / 64

// stage one K-64 tile: per wave 32 rows of A and of B (2 issues each, 16 rows/issue)
__device__ inline void stage(const char* __restrict__ xq, const char* __restrict__ wqT,
                             int m0, int n0, int kbase, char* buf, int w, int lane) {
  const int rl = lane >> 2;
  const int kc = ((lane & 3) ^ ((lane >> 3) & 3)) * 16;   // chunk = pos ^ f(row)
  #pragma unroll
  for (int i = 0; i < 2; ++i) {
    const int r0 = w * 32 + i * 16;
    gload16(xq + (size_t)(m0 + r0 + rl) * D_DIM + kbase + kc, buf + r0 * 64);
    gload16(wqT + (size_t)(n0 + r0 + rl) * D_DIM + kbase + kc, buf + 8192 + r0 * 64);
  }
}

__global__ __launch_bounds__(256, 4) void k_gemm(const char* __restrict__ xq,
                                                 const char* __restrict__ wqT,
                                                 const float* __restrict__ ws_f,
                                                 float* __restrict__ out) {
  __shared__ __align__(16) char lds[2 * 16384];   // buf b: A at b*16384, B at +8192
  const int t = threadIdx.x;
  const int lane = t & 63, w = t >> 6;
  const int wm = w >> 1, wn = w & 1;
  // XCD-chunked swizzle: each XCD gets 16 consecutive n-panels x all 8 m-panels.
  const int nid = (blockIdx.x & 7) * 128 + (blockIdx.x >> 3);
  const int m0 = (nid & 7) * 128;
  const int n0 = (nid >> 3) * 128;

  // prologue: stage tile 0 into buf 0; scales reduce under the loads
  stage(xq, wqT, m0, n0, 0, &lds[0], w, lane);
  float sx_u, st, s, q1;
  compute_scales(ws_f, lane, sx_u, st, s, q1);

  i32x4 acc[4][4] = {};

  for (int T = 0; T < NT; ++T) {
    char* buf = &lds[(T & 1) * 16384];
    asm volatile("s_waitcnt vmcnt(0)" ::: "memory");   // tile T landed (mine)
    __builtin_amdgcn_s_barrier();                      // all landed; all done reading buf^1
    if (T + 1 < NT)
      stage(xq, wqT, m0, n0, (T + 1) * 64, &lds[((T + 1) & 1) * 16384], w, lane);
    i32x4 af[4], bfr[4];
    #pragma unroll
    for (int f = 0; f < 4; ++f) {
      const int ra = wm * 64 + f * 16 + (lane & 15);
      af[f] = *(const i32x4*)&buf[ra * 64 + (((lane >> 4) ^ ((ra >> 1) & 3))) * 16];
      const int rb = wn * 64 + f * 16 + (lane & 15);
      bfr[f] = *(const i32x4*)&buf[8192 + rb * 64 + (((lane >> 4) ^ ((rb >> 1) & 3))) * 16];
    }
    __builtin_amdgcn_s_setprio(1);
    #pragma unroll
    for (int fm = 0; fm < 4; ++fm)
      #pragma unroll
      for (int fn = 0; fn < 4; ++fn)
        acc[fm][fn] = __builtin_amdgcn_mfma_i32_16x16x64_i8(af[fm], bfr[fn], acc[fm][fn], 0, 0, 0);
    __builtin_amdgcn_s_setprio(0);
    __builtin_amdgcn_sched_barrier(0);
  }

  // epilogue: C/D layout col=lane&15, row=(lane>>4)*4+reg; bias term folded in
  #pragma unroll
  for (int fn = 0; fn < 4; ++fn) {
    const int col = n0 + wn * 64 + fn * 16 + (lane & 15);
    const float ba = 32.0f * q1 * rintf(ws_f[IDX_BIAS + col] / st);
    #pragma unroll
    for (int fm = 0; fm < 4; ++fm) {
      const int rbase = m0 + wm * 64 + fm * 16 + ((lane >> 4) * 4);
      #pragma unroll
      for (int r = 0; r < 4; ++r)
        out[(size_t)(rbase + r) * N_DIM + col] = ((float)acc[fm][fn][r] + ba) * s;
    }
  }
}

extern "C" void kernel_launch(void* const* d_in, const int* in_sizes, int n_in,
                              void* d_out, int out_size, void* d_ws, size_t ws_size,
                              hipStream_t stream) {
  const float* x = (const float*)d_in[0];
  const float* w = (const float*)d_in[1];
  float* out = (float*)d_out;
  char* ws = (char*)d_ws;
  float* ws_f = (float*)ws;
  unsigned* xq = (unsigned*)(ws + OFF_XQ);
  unsigned* wqT = (unsigned*)(ws + OFF_WQT);

  hipLaunchKernelGGL(k_stats, dim3(WSTAT_BLOCKS + XMAX_BLOCKS), dim3(256), 0, stream,
                     x, w, ws_f);
  hipLaunchKernelGGL(k_quant, dim3(QX_BLOCKS + 2048), dim3(256), 0, stream,
                     x, w, ws_f, xq, wqT);
  hipLaunchKernelGGL(k_gemm, dim3((B_DIM / 128) * (N_DIM / 128)), dim3(256), 0, stream,
                     (const char*)xq, (const char*)wqT, ws_f, out);
}